// Round 1
// baseline (284.764 us; speedup 1.0000x reference)
//
#include <hip/hip_runtime.h>

// x: (b=32, t=24, d=10, m=64, n=128) fp32 ; out: (b=32, s=12, 1, m=64, n=128) fp32
//
// The EMA scan is LINEAR with compile-time-constant coefficients:
//   pred_s = sum_j A[s][j] * x[b, j, 0, m, n]
// where A (12x24) is obtained by symbolically expanding the 12-step recurrence
// at COMPILE TIME (constexpr). This kills the serial step dependence, the 276
// register-shift movs, and the runtime coefficient build.
// float4 vectorization: one thread per (b, mn/4) -> 24 dwordx4 loads, 12 dwordx4
// stores, 12 independent 24-term dot products (ILP = 4 comps x 12 outputs).

#define B 32
#define T 24
#define D 10
#define M 64
#define N 128
#define S_OUT 12
#define MN (M * N)                       // 8192
#define MN4 (MN / 4)                     // 2048 float4 per (b,t,d) slice
#define IN_T_STRIDE4 (D * MN / 4)        // 20480
#define IN_B_STRIDE4 (T * D * MN / 4)    // 491520
#define OUT_B_STRIDE4 (S_OUT * MN / 4)   // 24576

struct CoefMat { float a[S_OUT][T]; };

__host__ __device__ constexpr CoefMat make_coefs() {
  // mu = 2/(T+1) = 0.08, q = 0.92
  constexpr float mu = 2.0f / (float)(T + 1);
  constexpr float q  = 1.0f - mu;
  float c[T] = {};
  {
    float rec[T] = {};
    float pw = 1.0f;                       // q^k
    for (int k = 0; k < T - 1; ++k) { rec[T - 2 - k] = mu * pw; pw *= q; }
    const float base = pw / (float)T;      // q^(T-1)/T
    for (int j = 0; j < T - 1; ++j) c[j] = base + rec[j];
    c[T - 1] = base;
  }
  // Expand the recurrence over the basis of the original 24 window elements.
  // wb[slot][basis] = coefficient of original x_basis in current window slot.
  CoefMat m = {};
  float wb[T][T] = {};
  for (int j = 0; j < T; ++j) wb[j][j] = 1.0f;
  for (int s = 0; s < S_OUT; ++s) {
    float pr[T] = {};
    for (int slot = 0; slot < T; ++slot)
      for (int bb = 0; bb < T; ++bb) pr[bb] += c[slot] * wb[slot][bb];
    for (int bb = 0; bb < T; ++bb) m.a[s][bb] = pr[bb];
    for (int slot = 0; slot < T - 1; ++slot)
      for (int bb = 0; bb < T; ++bb) wb[slot][bb] = wb[slot + 1][bb];
    for (int bb = 0; bb < T; ++bb) wb[T - 1][bb] = pr[bb];
  }
  return m;
}

__global__ __launch_bounds__(128) void moving_avg_kernel(
    const float4* __restrict__ x4, float4* __restrict__ out4) {
  constexpr CoefMat AM = make_coefs();   // fully compile-time; folds to literals

  const int tid = blockIdx.x * blockDim.x + threadIdx.x;  // 0 .. 65535
  const int mn4 = tid & (MN4 - 1);
  const int b   = tid >> 11;             // tid / 2048

  // Coalesced 16B/lane loads of the 24-deep window (d = 0 slice).
  const float4* xp = x4 + (long)b * IN_B_STRIDE4 + mn4;
  float4 w[T];
#pragma unroll
  for (int t = 0; t < T; ++t) w[t] = xp[(long)t * IN_T_STRIDE4];

  float4* op = out4 + (long)b * OUT_B_STRIDE4 + mn4;
#pragma unroll
  for (int s = 0; s < S_OUT; ++s) {
    float ax = 0.0f, ay = 0.0f, az = 0.0f, aw = 0.0f;
#pragma unroll
    for (int j = 0; j < T; ++j) {
      const float cj = AM.a[s][j];
      ax = fmaf(w[j].x, cj, ax);
      ay = fmaf(w[j].y, cj, ay);
      az = fmaf(w[j].z, cj, az);
      aw = fmaf(w[j].w, cj, aw);
    }
    op[(long)s * MN4] = make_float4(ax, ay, az, aw);
  }
}

extern "C" void kernel_launch(void* const* d_in, const int* in_sizes, int n_in,
                              void* d_out, int out_size, void* d_ws, size_t ws_size,
                              hipStream_t stream) {
  const float4* x4 = (const float4*)d_in[0];
  float4* out4 = (float4*)d_out;
  const int total = B * MN4;             // 65536 threads
  moving_avg_kernel<<<total / 128, 128, 0, stream>>>(x4, out4);
}